// Round 2
// 761.318 us; speedup vs baseline: 1.0231x; 1.0231x over previous
//
#include <hip/hip_runtime.h>
#include <math.h>

#define SIGMA 0.05f

// ---------------------------------------------------------------------------
// fc_tanh: out[b,j] = tanh(in[b,:] @ W[:,j] + bias[j]),  in:[1024,256] W:[256,256]
// 4-row tiled: one block per 4 rows, 256 threads (one per output j).
// W traffic drops 1024*256KB -> 256*256KB = 64 MB (L2-served).
// LDS reads are float4 broadcasts (ds_read_b128, wave-uniform address).
// Per-accumulator FMA order is k-ascending -> bitwise identical to 1-row version.
// Also zeroes the argmax accumulator (stream-ordered before the argmax kernel).
// ---------------------------------------------------------------------------
__global__ __launch_bounds__(256) void fc_tanh_kernel(
    const float* __restrict__ in, const float* __restrict__ W,
    const float* __restrict__ bias, float* __restrict__ out,
    int* acc_zero)
{
    __shared__ __align__(16) float s[4][256];
    const int tid = threadIdx.x;
    const int row0 = blockIdx.x * 4;
#pragma unroll
    for (int r = 0; r < 4; ++r)
        s[r][tid] = in[(row0 + r) * 256 + tid];
    __syncthreads();
    const float bb = bias[tid];
    float a0 = bb, a1 = bb, a2 = bb, a3 = bb;
    for (int k = 0; k < 256; k += 4) {
        const float w0 = W[(k + 0) * 256 + tid];
        const float w1 = W[(k + 1) * 256 + tid];
        const float w2 = W[(k + 2) * 256 + tid];
        const float w3 = W[(k + 3) * 256 + tid];
        const float4 s0 = *(const float4*)&s[0][k];
        const float4 s1 = *(const float4*)&s[1][k];
        const float4 s2 = *(const float4*)&s[2][k];
        const float4 s3 = *(const float4*)&s[3][k];
        a0 = fmaf(s0.x, w0, a0); a0 = fmaf(s0.y, w1, a0);
        a0 = fmaf(s0.z, w2, a0); a0 = fmaf(s0.w, w3, a0);
        a1 = fmaf(s1.x, w0, a1); a1 = fmaf(s1.y, w1, a1);
        a1 = fmaf(s1.z, w2, a1); a1 = fmaf(s1.w, w3, a1);
        a2 = fmaf(s2.x, w0, a2); a2 = fmaf(s2.y, w1, a2);
        a2 = fmaf(s2.z, w2, a2); a2 = fmaf(s2.w, w3, a2);
        a3 = fmaf(s3.x, w0, a3); a3 = fmaf(s3.y, w1, a3);
        a3 = fmaf(s3.z, w2, a3); a3 = fmaf(s3.w, w3, a3);
    }
    out[(row0 + 0) * 256 + tid] = tanhf(a0);
    out[(row0 + 1) * 256 + tid] = tanhf(a1);
    out[(row0 + 2) * 256 + tid] = tanhf(a2);
    out[(row0 + 3) * 256 + tid] = tanhf(a3);
    if (acc_zero != nullptr && blockIdx.x == 0 && tid == 0) *acc_zero = 0;
}

// ---------------------------------------------------------------------------
// fc3: logits[b,d] = h2[b,:] @ W3[:,d] + b3[d],  h2:[1024,256] W3:[256,1024]
// block = 256 threads computes an 8-row x 256-col tile. grid = (4, 128).
// Inner loop unrolled by 4 with float4 LDS broadcasts.
// ---------------------------------------------------------------------------
__global__ __launch_bounds__(256) void fc3_kernel(
    const float* __restrict__ h2, const float* __restrict__ W3,
    const float* __restrict__ b3, float* __restrict__ logits)
{
    __shared__ __align__(16) float s[8][256];
    const int tid = threadIdx.x;
    const int col = blockIdx.x * 256 + tid;
    const int row0 = blockIdx.y * 8;
#pragma unroll
    for (int r = 0; r < 8; ++r)
        s[r][tid] = h2[(row0 + r) * 256 + tid];
    __syncthreads();
    float acc[8];
    const float bb = b3[col];
#pragma unroll
    for (int r = 0; r < 8; ++r) acc[r] = bb;
    for (int k = 0; k < 256; k += 4) {
        const float w0 = W3[(size_t)(k + 0) * 1024 + col];
        const float w1 = W3[(size_t)(k + 1) * 1024 + col];
        const float w2 = W3[(size_t)(k + 2) * 1024 + col];
        const float w3 = W3[(size_t)(k + 3) * 1024 + col];
#pragma unroll
        for (int r = 0; r < 8; ++r) {
            const float4 sv = *(const float4*)&s[r][k];
            acc[r] = fmaf(sv.x, w0, acc[r]);
            acc[r] = fmaf(sv.y, w1, acc[r]);
            acc[r] = fmaf(sv.z, w2, acc[r]);
            acc[r] = fmaf(sv.w, w3, acc[r]);
        }
    }
#pragma unroll
    for (int r = 0; r < 8; ++r)
        logits[(size_t)(row0 + r) * 1024 + col] = acc[r];
}

// ---------------------------------------------------------------------------
// softmax in-place over rows of [1024,1024]. One block per row, 4 elems/thread.
// ---------------------------------------------------------------------------
__global__ __launch_bounds__(256) void softmax_kernel(float* __restrict__ logits)
{
    __shared__ float red[4];
    const int b = blockIdx.x, tid = threadIdx.x;
    const int lane = tid & 63, wave = tid >> 6;
    float* row = logits + (size_t)b * 1024;
    float4 v = *(const float4*)(row + tid * 4);

    float m = fmaxf(fmaxf(v.x, v.y), fmaxf(v.z, v.w));
#pragma unroll
    for (int off = 1; off < 64; off <<= 1) m = fmaxf(m, __shfl_xor(m, off));
    if (lane == 0) red[wave] = m;
    __syncthreads();
    const float M = fmaxf(fmaxf(red[0], red[1]), fmaxf(red[2], red[3]));

    float4 e;
    e.x = expf(v.x - M); e.y = expf(v.y - M);
    e.z = expf(v.z - M); e.w = expf(v.w - M);
    float ssum = e.x + e.y + e.z + e.w;
#pragma unroll
    for (int off = 1; off < 64; off <<= 1) ssum += __shfl_xor(ssum, off);
    __syncthreads();               // red reuse
    if (lane == 0) red[wave] = ssum;
    __syncthreads();
    const float inv = 1.0f / (red[0] + red[1] + red[2] + red[3]);
    e.x *= inv; e.y *= inv; e.z *= inv; e.w *= inv;
    *(float4*)(row + tid * 4) = e;
}

// ---------------------------------------------------------------------------
// argmax scan: for each (b,n) find argmax_d(probs[b,d] + SIGMA*noise[b,n,d]),
// accumulate exact integer sum of indices. grid = B*4 blocks, each block does
// 32 n-values for one b (one n per wave per iteration). Noise read = 512 MiB,
// fully coalesced float4 — this kernel is the HBM-bound floor of the problem.
// ---------------------------------------------------------------------------
#define NSPLIT 4
__global__ __launch_bounds__(256) void argmax_kernel(
    const float* __restrict__ probs, const float* __restrict__ noise,
    int* __restrict__ acc)
{
    __shared__ float ps[1024];
    __shared__ int wsum[4];
    const int b = blockIdx.x / NSPLIT;
    const int part = blockIdx.x % NSPLIT;
    const int tid = threadIdx.x;
    const int lane = tid & 63, wave = tid >> 6;

    for (int i = tid; i < 1024; i += 256)
        ps[i] = probs[(size_t)b * 1024 + i];
    __syncthreads();

    const int nper = 128 / NSPLIT;  // 32
    int mysum = 0;
    for (int ni = wave; ni < nper; ni += 4) {
        const int n = part * nper + ni;
        const float* __restrict__ np_ = noise + ((size_t)b * 128 + n) * 1024;

        // lane covers float4 chunks lane, lane+64, lane+128, lane+192
        const float4 n0 = *(const float4*)(np_ + (size_t)(lane        ) * 4);
        const float4 n1 = *(const float4*)(np_ + (size_t)(lane +  64) * 4);
        const float4 n2 = *(const float4*)(np_ + (size_t)(lane + 128) * 4);
        const float4 n3 = *(const float4*)(np_ + (size_t)(lane + 192) * 4);
        const float4 p0 = *(const float4*)(ps + (lane        ) * 4);
        const float4 p1 = *(const float4*)(ps + (lane +  64) * 4);
        const float4 p2 = *(const float4*)(ps + (lane + 128) * 4);
        const float4 p3 = *(const float4*)(ps + (lane + 192) * 4);

        float best = -1e30f; int bidx = 0;
        // strict > keeps the lowest d on ties (in-lane d is visited ascending)
#define CHK(val, d) { float _v = (val); if (_v > best) { best = _v; bidx = (d); } }
        int d0 = lane * 4;
        CHK(fmaf(n0.x, SIGMA, p0.x), d0 + 0); CHK(fmaf(n0.y, SIGMA, p0.y), d0 + 1);
        CHK(fmaf(n0.z, SIGMA, p0.z), d0 + 2); CHK(fmaf(n0.w, SIGMA, p0.w), d0 + 3);
        d0 = (lane + 64) * 4;
        CHK(fmaf(n1.x, SIGMA, p1.x), d0 + 0); CHK(fmaf(n1.y, SIGMA, p1.y), d0 + 1);
        CHK(fmaf(n1.z, SIGMA, p1.z), d0 + 2); CHK(fmaf(n1.w, SIGMA, p1.w), d0 + 3);
        d0 = (lane + 128) * 4;
        CHK(fmaf(n2.x, SIGMA, p2.x), d0 + 0); CHK(fmaf(n2.y, SIGMA, p2.y), d0 + 1);
        CHK(fmaf(n2.z, SIGMA, p2.z), d0 + 2); CHK(fmaf(n2.w, SIGMA, p2.w), d0 + 3);
        d0 = (lane + 192) * 4;
        CHK(fmaf(n3.x, SIGMA, p3.x), d0 + 0); CHK(fmaf(n3.y, SIGMA, p3.y), d0 + 1);
        CHK(fmaf(n3.z, SIGMA, p3.z), d0 + 2); CHK(fmaf(n3.w, SIGMA, p3.w), d0 + 3);
#undef CHK

        // 64-lane butterfly: max value, ties -> lowest index
#pragma unroll
        for (int off = 1; off < 64; off <<= 1) {
            const float ov = __shfl_xor(best, off);
            const int   oi = __shfl_xor(bidx, off);
            if (ov > best || (ov == best && oi < bidx)) { best = ov; bidx = oi; }
        }
        mysum += bidx;
    }
    if (lane == 0) wsum[wave] = mysum;
    __syncthreads();
    if (tid == 0)
        atomicAdd(acc, wsum[0] + wsum[1] + wsum[2] + wsum[3]);
}

// ---------------------------------------------------------------------------
// value head: Q[b] = tanh([obs[b,:], c] @ Wv1 + bv1) @ Wv2 + bv2,
// c = (float)acc / 128. 4-row tiled like fc_tanh: Wv1 traffic 256MB -> 64MB.
// Reduction structure (butterfly then 4-wave LDS sum) identical to 1-row
// version per row -> bitwise identical Q.
// ---------------------------------------------------------------------------
__global__ __launch_bounds__(256) void value_kernel(
    const float* __restrict__ obs, const float* __restrict__ Wv1,
    const float* __restrict__ bv1, const float* __restrict__ Wv2,
    const float* __restrict__ bv2, const int* __restrict__ acc,
    float* __restrict__ Q)
{
    __shared__ __align__(16) float s[4][256];
    __shared__ float red[4][4];
    const int tid = threadIdx.x;
    const int lane = tid & 63, wave = tid >> 6;
    const int row0 = blockIdx.x * 4;
#pragma unroll
    for (int r = 0; r < 4; ++r)
        s[r][tid] = obs[(row0 + r) * 256 + tid];
    __syncthreads();
    const float c = (float)(*acc) * (1.0f / 128.0f);
    const float base = bv1[tid] + c * Wv1[256 * 256 + tid];   // last row of Wv1 (k = OBS)
    float a0 = base, a1 = base, a2 = base, a3 = base;
    for (int k = 0; k < 256; k += 4) {
        const float w0 = Wv1[(k + 0) * 256 + tid];
        const float w1 = Wv1[(k + 1) * 256 + tid];
        const float w2 = Wv1[(k + 2) * 256 + tid];
        const float w3 = Wv1[(k + 3) * 256 + tid];
        const float4 s0 = *(const float4*)&s[0][k];
        const float4 s1 = *(const float4*)&s[1][k];
        const float4 s2 = *(const float4*)&s[2][k];
        const float4 s3 = *(const float4*)&s[3][k];
        a0 = fmaf(s0.x, w0, a0); a0 = fmaf(s0.y, w1, a0);
        a0 = fmaf(s0.z, w2, a0); a0 = fmaf(s0.w, w3, a0);
        a1 = fmaf(s1.x, w0, a1); a1 = fmaf(s1.y, w1, a1);
        a1 = fmaf(s1.z, w2, a1); a1 = fmaf(s1.w, w3, a1);
        a2 = fmaf(s2.x, w0, a2); a2 = fmaf(s2.y, w1, a2);
        a2 = fmaf(s2.z, w2, a2); a2 = fmaf(s2.w, w3, a2);
        a3 = fmaf(s3.x, w0, a3); a3 = fmaf(s3.y, w1, a3);
        a3 = fmaf(s3.z, w2, a3); a3 = fmaf(s3.w, w3, a3);
    }
    const float w2v = Wv2[tid];
    float v0 = tanhf(a0) * w2v;
    float v1 = tanhf(a1) * w2v;
    float v2 = tanhf(a2) * w2v;
    float v3 = tanhf(a3) * w2v;
#pragma unroll
    for (int off = 1; off < 64; off <<= 1) {
        v0 += __shfl_xor(v0, off);
        v1 += __shfl_xor(v1, off);
        v2 += __shfl_xor(v2, off);
        v3 += __shfl_xor(v3, off);
    }
    if (lane == 0) {
        red[0][wave] = v0; red[1][wave] = v1;
        red[2][wave] = v2; red[3][wave] = v3;
    }
    __syncthreads();
    if (tid < 4)
        Q[row0 + tid] = red[tid][0] + red[tid][1] + red[tid][2] + red[tid][3] + bv2[0];
}

// ---------------------------------------------------------------------------
extern "C" void kernel_launch(void* const* d_in, const int* in_sizes, int n_in,
                              void* d_out, int out_size, void* d_ws, size_t ws_size,
                              hipStream_t stream)
{
    const float* obs   = (const float*)d_in[0];
    const float* noise = (const float*)d_in[1];
    const float* W1    = (const float*)d_in[2];
    const float* b1    = (const float*)d_in[3];
    const float* W2    = (const float*)d_in[4];
    const float* b2    = (const float*)d_in[5];
    const float* W3    = (const float*)d_in[6];
    const float* b3    = (const float*)d_in[7];
    const float* Wv1   = (const float*)d_in[8];
    const float* bv1   = (const float*)d_in[9];
    const float* Wv2   = (const float*)d_in[10];
    const float* bv2   = (const float*)d_in[11];
    float* Q = (float*)d_out;

    // workspace layout (floats): h1[256K] h2[256K] logits/probs[1M] acc[1 int]
    float* ws     = (float*)d_ws;
    float* h1     = ws;
    float* h2     = h1 + 1024 * 256;
    float* logits = h2 + 1024 * 256;
    int*   acc    = (int*)(logits + 1024 * 1024);

    fc_tanh_kernel<<<256, 256, 0, stream>>>(obs, W1, b1, h1, acc);
    fc_tanh_kernel<<<256, 256, 0, stream>>>(h1, W2, b2, h2, nullptr);
    fc3_kernel<<<dim3(4, 128), 256, 0, stream>>>(h2, W3, b3, logits);
    softmax_kernel<<<1024, 256, 0, stream>>>(logits);
    argmax_kernel<<<1024 * NSPLIT, 256, 0, stream>>>(logits, noise, acc);
    value_kernel<<<256, 256, 0, stream>>>(obs, Wv1, bv1, Wv2, bv2, acc, Q);
}